// Round 4
// baseline (328.370 us; speedup 1.0000x reference)
//
#include <hip/hip_runtime.h>

// VQSpeaker: obs[32,2048,128] -> 3-layer MLP -> x[65536,64] -> VQ argmin over
// codebook[2048,64] -> (msg = codebook[idx], idx, cmt_loss).
//
// Round 4 vq: two-pass MFMA screen (pass A: max-only, pass B: thresholded
// candidate collect, pass C: exact fp32 rescore), codebook tiles staged once
// per block in double-buffered LDS shared by 4 waves.
//
// d_out layout (float32): msg[4194304] | idx[65536] (as float) | loss[1]
// d_ws: e2[2048] f32 | cb_hi_perm[2048*64] bf16 | cb_lo_perm[2048*64] bf16

#define NPTS    65536
#define IN_DIM  128
#define HID     64
#define OUT_DIM 64
#define CB_N    2048
#define MSG_ELEMS (NPTS * OUT_DIM)
#define LOSS_SCALE (1.0f / 4194304.0f)
#define MARG_S 0.25f       // s'-space margin (= 0.5 in d-space, proven in R3)
#define CAND_CAP 3072
#define VQ_PTS 128         // points per block

typedef __attribute__((ext_vector_type(8))) short short8;
typedef __attribute__((ext_vector_type(4))) float f32x4;

__device__ __forceinline__ unsigned short f2bf(float f) {
    unsigned u = __float_as_uint(f);
    u += 0x7FFF + ((u >> 16) & 1);          // RN-even to bf16
    return (unsigned short)(u >> 16);
}
__device__ __forceinline__ float bf2f(unsigned short h) {
    return __uint_as_float((unsigned)h << 16);
}

__global__ void zero_loss_kernel(float* __restrict__ loss) { *loss = 0.0f; }

__global__ __launch_bounds__(256) void e2_kernel(
    const float* __restrict__ codebook, float* __restrict__ e2)
{
    const int c = blockIdx.x * 256 + threadIdx.x;
    const float4* row = (const float4*)(codebook + (long)c * OUT_DIM);
    float s = 0.0f;
    #pragma unroll
    for (int m = 0; m < 16; ++m) {
        const float4 v = row[m];
        s += v.x * v.x + v.y * v.y + v.z * v.z + v.w * v.w;
    }
    e2[c] = s;
}

// Permute codebook into MFMA B-fragment order (verified in R3), split hi/lo.
// (tile,half,lane,j): cb[tile*16+(lane&15)][half*32+(lane>>4)*8+j]
// dst = ((tile*2+half)*64 + lane)*8 + j
__global__ __launch_bounds__(256) void prep_kernel(
    const float* __restrict__ cb,
    unsigned short* __restrict__ cbh, unsigned short* __restrict__ cbl)
{
    const int id = blockIdx.x * 256 + threadIdx.x;  // 0..4095: (code n, half h)
    const int n = id >> 1, h = id & 1;
    const int t = n >> 4, l15 = n & 15;
    const float* src = cb + (long)n * OUT_DIM + h * 32;
    #pragma unroll
    for (int quad = 0; quad < 4; ++quad) {
        short8 hi, lo;
        #pragma unroll
        for (int j = 0; j < 8; ++j) {
            const float f = src[quad * 8 + j];
            const unsigned short hb = f2bf(f);
            hi[j] = (short)hb;
            lo[j] = (short)f2bf(f - bf2f(hb));
        }
        const long dst = ((long)(t * 2 + h) * 64 + quad * 16 + l15) * 8;
        *(short8*)(cbh + dst) = hi;
        *(short8*)(cbl + dst) = lo;
    }
}

// ---------------- MLP: unchanged (passing numerics) ----------------
__global__ __launch_bounds__(256) void mlp_kernel(
    const float* __restrict__ obs,
    const float* __restrict__ W1, const float* __restrict__ b1,
    const float* __restrict__ W2, const float* __restrict__ b2,
    const float* __restrict__ W3, const float* __restrict__ b3,
    float* __restrict__ xout)
{
    __shared__ float wbuf[8448];
    __shared__ float h1_s[64 * 68];
    __shared__ float bias_s[64];

    const int t = threadIdx.x;
    const long base = (long)blockIdx.x * 64;
    const int pt = t & 15, jt = t >> 4;

    #pragma unroll
    for (int m = 0; m < 32; ++m) wbuf[t + 256 * m] = W1[t + 256 * m];
    if (t < 64) bias_s[t] = b1[t];
    __syncthreads();

    float acc[4][4];
    #pragma unroll
    for (int i = 0; i < 4; ++i)
        #pragma unroll
        for (int j = 0; j < 4; ++j) acc[i][j] = 0.0f;

    const float* obs_rows[4];
    #pragma unroll
    for (int i = 0; i < 4; ++i) obs_rows[i] = obs + (base + pt + 16 * i) * IN_DIM;

    for (int k = 0; k < 128; k += 4) {
        float4 ov[4];
        #pragma unroll
        for (int i = 0; i < 4; ++i) ov[i] = *(const float4*)(obs_rows[i] + k);
        #pragma unroll
        for (int jj = 0; jj < 4; ++jj) {
            const int j = jt + 16 * jj;
            const float w0 = wbuf[(k + 0) * 64 + j];
            const float w1v = wbuf[(k + 1) * 64 + j];
            const float w2v = wbuf[(k + 2) * 64 + j];
            const float w3v = wbuf[(k + 3) * 64 + j];
            #pragma unroll
            for (int i = 0; i < 4; ++i) {
                acc[i][jj] = fmaf(ov[i].x, w0, acc[i][jj]);
                acc[i][jj] = fmaf(ov[i].y, w1v, acc[i][jj]);
                acc[i][jj] = fmaf(ov[i].z, w2v, acc[i][jj]);
                acc[i][jj] = fmaf(ov[i].w, w3v, acc[i][jj]);
            }
        }
    }
    #pragma unroll
    for (int i = 0; i < 4; ++i)
        #pragma unroll
        for (int jj = 0; jj < 4; ++jj) {
            const float v = acc[i][jj] + bias_s[jt + 16 * jj];
            h1_s[(pt + 16 * i) * 68 + jt + 16 * jj] = v > 0.0f ? v : 0.0f;
        }
    __syncthreads();

    #pragma unroll
    for (int m = 0; m < 16; ++m) wbuf[t + 256 * m] = W2[t + 256 * m];
    if (t < 64) bias_s[t] = b2[t];
    __syncthreads();

    float* h2_s = wbuf + 4096;
    #pragma unroll
    for (int i = 0; i < 4; ++i)
        #pragma unroll
        for (int j = 0; j < 4; ++j) acc[i][j] = 0.0f;
    for (int k = 0; k < 64; k += 4) {
        float4 hv[4];
        #pragma unroll
        for (int i = 0; i < 4; ++i) hv[i] = *(const float4*)&h1_s[(pt + 16 * i) * 68 + k];
        #pragma unroll
        for (int jj = 0; jj < 4; ++jj) {
            const int j = jt + 16 * jj;
            const float w0 = wbuf[(k + 0) * 64 + j];
            const float w1v = wbuf[(k + 1) * 64 + j];
            const float w2v = wbuf[(k + 2) * 64 + j];
            const float w3v = wbuf[(k + 3) * 64 + j];
            #pragma unroll
            for (int i = 0; i < 4; ++i) {
                acc[i][jj] = fmaf(hv[i].x, w0, acc[i][jj]);
                acc[i][jj] = fmaf(hv[i].y, w1v, acc[i][jj]);
                acc[i][jj] = fmaf(hv[i].z, w2v, acc[i][jj]);
                acc[i][jj] = fmaf(hv[i].w, w3v, acc[i][jj]);
            }
        }
    }
    #pragma unroll
    for (int i = 0; i < 4; ++i)
        #pragma unroll
        for (int jj = 0; jj < 4; ++jj) {
            const float v = acc[i][jj] + bias_s[jt + 16 * jj];
            h2_s[(pt + 16 * i) * 68 + jt + 16 * jj] = v > 0.0f ? v : 0.0f;
        }
    __syncthreads();

    #pragma unroll
    for (int m = 0; m < 16; ++m) wbuf[t + 256 * m] = W3[t + 256 * m];
    if (t < 64) bias_s[t] = b3[t];
    __syncthreads();

    #pragma unroll
    for (int i = 0; i < 4; ++i)
        #pragma unroll
        for (int j = 0; j < 4; ++j) acc[i][j] = 0.0f;
    for (int k = 0; k < 64; k += 4) {
        float4 hv[4];
        #pragma unroll
        for (int i = 0; i < 4; ++i) hv[i] = *(const float4*)&h2_s[(pt + 16 * i) * 68 + k];
        #pragma unroll
        for (int jj = 0; jj < 4; ++jj) {
            const int j = jt + 16 * jj;
            const float w0 = wbuf[(k + 0) * 64 + j];
            const float w1v = wbuf[(k + 1) * 64 + j];
            const float w2v = wbuf[(k + 2) * 64 + j];
            const float w3v = wbuf[(k + 3) * 64 + j];
            #pragma unroll
            for (int i = 0; i < 4; ++i) {
                acc[i][jj] = fmaf(hv[i].x, w0, acc[i][jj]);
                acc[i][jj] = fmaf(hv[i].y, w1v, acc[i][jj]);
                acc[i][jj] = fmaf(hv[i].z, w2v, acc[i][jj]);
                acc[i][jj] = fmaf(hv[i].w, w3v, acc[i][jj]);
            }
        }
    }
    #pragma unroll
    for (int i = 0; i < 4; ++i)
        #pragma unroll
        for (int jj = 0; jj < 4; ++jj)
            h1_s[(pt + 16 * i) * 68 + jt + 16 * jj] = acc[i][jj] + bias_s[jt + 16 * jj];
    __syncthreads();

    float4* og = (float4*)(xout + base * OUT_DIM);
    #pragma unroll
    for (int m = 0; m < 4; ++m) {
        const int v = t + 256 * m;
        const int p = v >> 4, k4 = v & 15;
        og[v] = *(const float4*)&h1_s[p * 68 + k4 * 4];
    }
}

// exact fp32 distance update (R2/R3 proven numerics)
__device__ __forceinline__ void exact_upd(
    const float* __restrict__ xr, const float* __restrict__ cb,
    const float* __restrict__ e2, int n, float& bd, int& bi)
{
    const float4* xp = (const float4*)xr;
    const float4* cp = (const float4*)(cb + (long)n * OUT_DIM);
    float a0 = 0.0f, a1 = 0.0f;
    #pragma unroll
    for (int m = 0; m < 16; ++m) {
        const float4 xv = xp[m], cv = cp[m];
        a0 = fmaf(xv.x, cv.x, a0); a1 = fmaf(xv.y, cv.y, a1);
        a0 = fmaf(xv.z, cv.z, a0); a1 = fmaf(xv.w, cv.w, a1);
    }
    const float ex = fmaf(-2.0f, a0 + a1, e2[n]);
    if (ex < bd || (ex == bd && n < bi)) { bd = ex; bi = n; }
}

// ---------------- VQ: 256 thr = 4 waves, 128 pts/block, LDS-staged tiles ----
__global__ __launch_bounds__(256) void vq_mfma(
    const float* __restrict__ cb,
    const unsigned short* __restrict__ cbhp,
    const unsigned short* __restrict__ cblp,
    const float* __restrict__ e2,
    float* __restrict__ msg,        // in: x, out: quantize
    float* __restrict__ idx_out,
    float* __restrict__ loss_out)
{
    __shared__ float4 dbuf[512];        // 2 bufs x 256 float4 (tile = 4KB)
    __shared__ float  e2h_s[2048];      // e2/2
    __shared__ float  red_s[4 * 32 * 16];
    __shared__ float  thr_s[VQ_PTS];
    __shared__ int    idx_sh[VQ_PTS];
    __shared__ int    cand[CAND_CAP];
    __shared__ int    cand_cnt;
    __shared__ float  wred[4];

    const int t = threadIdx.x, lane = t & 63, w = t >> 6;
    const int m = lane & 15, quad = lane >> 4;
    const long base = (long)blockIdx.x * VQ_PTS;

    // A-frags for 2 M-tiles (32 points/wave), built once (R3-verified layout)
    short8 ah[2][2], al[2][2];          // [mtile][khalf]
    #pragma unroll
    for (int mt = 0; mt < 2; ++mt) {
        const float* xrow = msg + (base + w * 32 + mt * 16 + m) * OUT_DIM;
        #pragma unroll
        for (int kh = 0; kh < 2; ++kh) {
            const float4 xa = *(const float4*)(xrow + kh * 32 + quad * 8);
            const float4 xb = *(const float4*)(xrow + kh * 32 + quad * 8 + 4);
            const float xs[8] = {xa.x, xa.y, xa.z, xa.w, xb.x, xb.y, xb.z, xb.w};
            #pragma unroll
            for (int j = 0; j < 8; ++j) {
                const unsigned short hb = f2bf(xs[j]);
                ah[mt][kh][j] = (short)hb;
                al[mt][kh][j] = (short)f2bf(xs[j] - bf2f(hb));
            }
        }
    }

    // staging source for this wave's chunk (w<2: hi, half=w&1; w>=2: lo)
    const float4* srcA = (const float4*)((w < 2) ? cbhp : cblp);
    const int half = w & 1;
    const int dstoff = w * 64 + lane;   // within a 256-float4 buffer

    // stage tile 0 -> buf 0; stage e2h; zero cand_cnt
    dbuf[dstoff] = srcA[half * 64 + lane];
    {
        const float4* e2f = (const float4*)e2;
        #pragma unroll
        for (int i = 0; i < 2; ++i) {
            const float4 v = e2f[t + 256 * i];
            float4 h; h.x = v.x * 0.5f; h.y = v.y * 0.5f;
            h.z = v.z * 0.5f; h.w = v.w * 0.5f;
            ((float4*)e2h_s)[t + 256 * i] = h;
        }
    }
    if (t == 0) cand_cnt = 0;
    __syncthreads();

    // ---- pass A: max-only screen ----
    float rmax[2][4];
    #pragma unroll
    for (int mt = 0; mt < 2; ++mt)
        #pragma unroll
        for (int r = 0; r < 4; ++r) rmax[mt][r] = -3.4e38f;

    for (int tt = 0; tt < 128; ++tt) {
        const int b = tt & 1;
        float4 nx;
        if (tt < 127) nx = srcA[((tt + 1) * 2 + half) * 64 + lane];
        const float e2h_v = e2h_s[tt * 16 + m];
        const short8* fb = (const short8*)dbuf;
        const short8 bh0 = fb[b * 256 + lane];
        const short8 bh1 = fb[b * 256 + 64 + lane];
        const short8 bl0 = fb[b * 256 + 128 + lane];
        const short8 bl1 = fb[b * 256 + 192 + lane];
        #pragma unroll
        for (int mt = 0; mt < 2; ++mt) {
            f32x4 acc0 = {-e2h_v, -e2h_v, -e2h_v, -e2h_v};   // fold -e2/2 into init
            f32x4 acc1 = {0.0f, 0.0f, 0.0f, 0.0f};
            acc0 = __builtin_amdgcn_mfma_f32_16x16x32_bf16(ah[mt][0], bh0, acc0, 0, 0, 0);
            acc0 = __builtin_amdgcn_mfma_f32_16x16x32_bf16(al[mt][0], bh0, acc0, 0, 0, 0);
            acc0 = __builtin_amdgcn_mfma_f32_16x16x32_bf16(ah[mt][0], bl0, acc0, 0, 0, 0);
            acc1 = __builtin_amdgcn_mfma_f32_16x16x32_bf16(ah[mt][1], bh1, acc1, 0, 0, 0);
            acc1 = __builtin_amdgcn_mfma_f32_16x16x32_bf16(al[mt][1], bh1, acc1, 0, 0, 0);
            acc1 = __builtin_amdgcn_mfma_f32_16x16x32_bf16(ah[mt][1], bl1, acc1, 0, 0, 0);
            #pragma unroll
            for (int r = 0; r < 4; ++r)
                rmax[mt][r] = fmaxf(rmax[mt][r], acc0[r] + acc1[r]);
        }
        if (tt < 127) dbuf[(1 - b) * 256 + dstoff] = nx;
        __syncthreads();
    }

    // per-point threshold
    #pragma unroll
    for (int mt = 0; mt < 2; ++mt)
        #pragma unroll
        for (int r = 0; r < 4; ++r)
            red_s[((w * 32 + mt * 16 + quad * 4 + r) << 4) | m] = rmax[mt][r];
    __syncthreads();
    if (t < VQ_PTS) {
        float mx = -3.4e38f;
        #pragma unroll
        for (int c = 0; c < 16; ++c) mx = fmaxf(mx, red_s[(t << 4) | c]);
        thr_s[t] = mx - MARG_S;
    }
    __syncthreads();

    float tv[2][4];
    #pragma unroll
    for (int mt = 0; mt < 2; ++mt)
        #pragma unroll
        for (int r = 0; r < 4; ++r)
            tv[mt][r] = thr_s[w * 32 + mt * 16 + quad * 4 + r];

    // ---- pass B: thresholded candidate collect (identical MFMA numerics) ----
    dbuf[dstoff] = srcA[half * 64 + lane];
    __syncthreads();
    for (int tt = 0; tt < 128; ++tt) {
        const int b = tt & 1;
        float4 nx;
        if (tt < 127) nx = srcA[((tt + 1) * 2 + half) * 64 + lane];
        const float e2h_v = e2h_s[tt * 16 + m];
        const short8* fb = (const short8*)dbuf;
        const short8 bh0 = fb[b * 256 + lane];
        const short8 bh1 = fb[b * 256 + 64 + lane];
        const short8 bl0 = fb[b * 256 + 128 + lane];
        const short8 bl1 = fb[b * 256 + 192 + lane];
        #pragma unroll
        for (int mt = 0; mt < 2; ++mt) {
            f32x4 acc0 = {-e2h_v, -e2h_v, -e2h_v, -e2h_v};
            f32x4 acc1 = {0.0f, 0.0f, 0.0f, 0.0f};
            acc0 = __builtin_amdgcn_mfma_f32_16x16x32_bf16(ah[mt][0], bh0, acc0, 0, 0, 0);
            acc0 = __builtin_amdgcn_mfma_f32_16x16x32_bf16(al[mt][0], bh0, acc0, 0, 0, 0);
            acc0 = __builtin_amdgcn_mfma_f32_16x16x32_bf16(ah[mt][0], bl0, acc0, 0, 0, 0);
            acc1 = __builtin_amdgcn_mfma_f32_16x16x32_bf16(ah[mt][1], bh1, acc1, 0, 0, 0);
            acc1 = __builtin_amdgcn_mfma_f32_16x16x32_bf16(al[mt][1], bh1, acc1, 0, 0, 0);
            acc1 = __builtin_amdgcn_mfma_f32_16x16x32_bf16(ah[mt][1], bl1, acc1, 0, 0, 0);
            #pragma unroll
            for (int r = 0; r < 4; ++r) {
                const float u = acc0[r] + acc1[r];
                if (u >= tv[mt][r]) {                        // rare
                    const int s = atomicAdd(&cand_cnt, 1);
                    if (s < CAND_CAP)
                        cand[s] = ((w * 32 + mt * 16 + quad * 4 + r) << 16)
                                  | (tt * 16 + m);
                }
            }
        }
        if (tt < 127) dbuf[(1 - b) * 256 + dstoff] = nx;
        __syncthreads();
    }

    // ---- pass C: exact rescore of candidates ----
    if (t < VQ_PTS) {
        const int p = t;
        float fbd = 3.4e38f; int fbi = 1 << 30;
        const float* xr = msg + (base + p) * OUT_DIM;        // still x
        const int L = min(cand_cnt, CAND_CAP);
        for (int l = 0; l < L; ++l) {
            const int pc = cand[l];
            if ((pc >> 16) == p)
                exact_upd(xr, cb, e2, pc & 0xFFFF, fbd, fbi);
        }
        idx_sh[p] = fbi;
        idx_out[base + p] = (float)fbi;
    }
    __syncthreads();

    // gather q, write msg, accumulate loss
    float lsum = 0.0f;
    float4* xg = (float4*)(msg + base * OUT_DIM);
    #pragma unroll
    for (int mm = 0; mm < 8; ++mm) {
        const int v = t + 256 * mm;
        const int p = v >> 4, k4 = v & 15;
        const int code = idx_sh[p];
        const float4 q = ((const float4*)(cb + (long)code * OUT_DIM))[k4];
        const float4 xv = xg[v];
        const float dx = q.x - xv.x, dy = q.y - xv.y;
        const float dz = q.z - xv.z, dw2 = q.w - xv.w;
        lsum += dx * dx + dy * dy + dz * dz + dw2 * dw2;
        xg[v] = q;
    }
    #pragma unroll
    for (int off = 32; off > 0; off >>= 1) lsum += __shfl_down(lsum, off, 64);
    if (lane == 0) wred[w] = lsum;
    __syncthreads();
    if (t == 0)
        atomicAdd(loss_out, (wred[0] + wred[1] + wred[2] + wred[3]) * LOSS_SCALE);
}

extern "C" void kernel_launch(void* const* d_in, const int* in_sizes, int n_in,
                              void* d_out, int out_size, void* d_ws, size_t ws_size,
                              hipStream_t stream) {
    const float* obs = (const float*)d_in[0];
    const float* W1  = (const float*)d_in[1];
    const float* b1  = (const float*)d_in[2];
    const float* W2  = (const float*)d_in[3];
    const float* b2  = (const float*)d_in[4];
    const float* W3  = (const float*)d_in[5];
    const float* b3  = (const float*)d_in[6];
    const float* cb  = (const float*)d_in[7];

    float* out  = (float*)d_out;
    float* msg  = out;                        // also x staging
    float* idxf = out + MSG_ELEMS;
    float* loss = out + MSG_ELEMS + NPTS;

    float*          e2  = (float*)d_ws;                       // 8 KB
    unsigned short* cbh = (unsigned short*)((char*)d_ws + 8192);
    unsigned short* cbl = cbh + CB_N * OUT_DIM;               // +256 KB each

    zero_loss_kernel<<<1, 1, 0, stream>>>(loss);
    e2_kernel<<<CB_N / 256, 256, 0, stream>>>(cb, e2);
    prep_kernel<<<16, 256, 0, stream>>>(cb, cbh, cbl);
    mlp_kernel<<<NPTS / 64, 256, 0, stream>>>(obs, W1, b1, W2, b2, W3, b3, msg);
    vq_mfma<<<NPTS / VQ_PTS, 256, 0, stream>>>(cb, cbh, cbl, e2, msg, idxf, loss);
}